// Round 3
// baseline (226.763 us; speedup 1.0000x reference)
//
#include <hip/hip_runtime.h>
#include <hip/hip_bf16.h>

#define F_ 16384
#define D_ 768
#define C_ 16
#define BS_ 512
#define M_ (F_*C_)
#define FPB_ 16   // f's per block in k_values

static __device__ __forceinline__ float bf2f(unsigned short u) {
    return __uint_as_float(((unsigned int)u) << 16);
}
static __device__ __forceinline__ unsigned short f2bf(float f) {
    return __bfloat16_as_ushort(__float2bfloat16(f));
}

// ---------------------------------------------------------------------------
// Transpose + downconvert: up_decoder fp32 [D, F] -> decT bf16 [F, D].
// 64(D) x 64(F) tile; float4 global loads, uint2 (4 x bf16) packed stores.
// (unchanged)
// ---------------------------------------------------------------------------
__global__ __launch_bounds__(256) void k_transpose_bf16(const float* __restrict__ in,
                                                        unsigned short* __restrict__ out) {
    __shared__ float tile[64][65];      // [d_local][f_local], +1 pad
    int c4 = threadIdx.x & 15;          // float4 column (f)
    int r  = threadIdx.x >> 4;          // 0..15 (d)
    int fbase = blockIdx.x * 64;
    int dbase = blockIdx.y * 64;
#pragma unroll
    for (int k = 0; k < 4; ++k) {
        int drow = r + k * 16;
        float4 v = *(const float4*)(in + (size_t)(dbase + drow) * F_ + fbase + c4 * 4);
        tile[drow][c4 * 4 + 0] = v.x;
        tile[drow][c4 * 4 + 1] = v.y;
        tile[drow][c4 * 4 + 2] = v.z;
        tile[drow][c4 * 4 + 3] = v.w;
    }
    __syncthreads();
    int dp = threadIdx.x & 15;          // uint2 index (4 d-values each)
    int fr = threadIdx.x >> 4;          // 0..15 (f)
#pragma unroll
    for (int k = 0; k < 4; ++k) {
        int frow = fr + k * 16;
        float v0 = tile[4 * dp + 0][frow];
        float v1 = tile[4 * dp + 1][frow];
        float v2 = tile[4 * dp + 2][frow];
        float v3 = tile[4 * dp + 3][frow];
        uint2 p;
        p.x = ((unsigned int)f2bf(v1) << 16) | (unsigned int)f2bf(v0);
        p.y = ((unsigned int)f2bf(v3) << 16) | (unsigned int)f2bf(v2);
        *(uint2*)(out + (size_t)(fbase + frow) * D_ + dbase + dp * 4) = p;
    }
}

// ---------------------------------------------------------------------------
// k_values v3: per-connection value dot(enc[f,:], decT[j,:]) over D=768.
// Latency-bound fix, simplified realization:
//   - block owns FPB_=16 consecutive f's; all 256 j-indices staged to LDS
//     once (coalesced, one barrier) so the j->gather chain is LDS-latency.
//   - explicit A/B double-buffer over f pairs: stage(f+1) issued before
//     compute(f), so every compute has the other buffer's 15 loads in
//     flight. Inline functions, full static unroll (no runtime indexing).
// Wave w handles connections 4w..4w+3 of each f (unchanged split).
// Output format unchanged: packed[m] = (bf16(value)<<16) | (u16)j.
// ---------------------------------------------------------------------------
static __device__ __forceinline__ void v_load_e(const float* __restrict__ enc,
                                                int fc, int lane, float4 e[3]) {
    const float4* erow = (const float4*)(enc + (size_t)fc * D_);
    e[0] = erow[lane];
    e[1] = erow[lane + 64];
    e[2] = erow[lane + 128];
}

static __device__ __forceinline__ void v_gather(const unsigned short* __restrict__ decT,
                                                const int* jsh, int ff, int wave,
                                                int lane, int js[4], ushort4 g[4][3]) {
#pragma unroll
    for (int t = 0; t < 4; ++t) {
        int j = jsh[(ff << 4) + (wave << 2) + t];
        js[t] = j;
        const ushort4* drow = (const ushort4*)(decT + (size_t)j * D_);
        g[t][0] = drow[lane];
        g[t][1] = drow[lane + 64];
        g[t][2] = drow[lane + 128];
    }
}

static __device__ __forceinline__ void v_compute(unsigned int* __restrict__ packed,
                                                 int fc, int wave, int lane,
                                                 const float4 e[3], const int js[4],
                                                 const ushort4 g[4][3]) {
#pragma unroll
    for (int t = 0; t < 4; ++t) {
        float acc = 0.f;
#pragma unroll
        for (int k = 0; k < 3; ++k) {
            float4  ev = e[k];
            ushort4 dv = g[t][k];
            acc += ev.x * bf2f(dv.x) + ev.y * bf2f(dv.y)
                 + ev.z * bf2f(dv.z) + ev.w * bf2f(dv.w);
        }
#pragma unroll
        for (int off = 32; off > 0; off >>= 1)
            acc += __shfl_down(acc, off, 64);
        if (lane == 0)
            packed[(fc << 4) + (wave << 2) + t] =
                ((unsigned int)f2bf(acc) << 16) | (unsigned int)js[t];
    }
}

__global__ __launch_bounds__(256) void k_values(const float* __restrict__ enc,
                                                const unsigned short* __restrict__ decT,
                                                const int* __restrict__ jidx,
                                                unsigned int* __restrict__ packed) {
    const int lane = threadIdx.x & 63;
    const int wave = threadIdx.x >> 6;        // 0..3
    const int f0 = blockIdx.x * FPB_;

    __shared__ int jsh[FPB_ * C_];            // 1 KB: all j's for this block
    jsh[threadIdx.x] = jidx[(f0 << 4) + threadIdx.x];
    __syncthreads();

    float4  eA[3], eB[3];
    int     jA[4], jB[4];
    ushort4 gA[4][3], gB[4][3];

    // prologue: A <- f0
    v_load_e(enc, f0, lane, eA);
    v_gather(decT, jsh, 0, wave, lane, jA, gA);

#pragma unroll
    for (int p = 0; p < FPB_ / 2; ++p) {
        // issue B loads for f(2p+1), then consume A (B in flight)
        v_load_e(enc, f0 + 2 * p + 1, lane, eB);
        v_gather(decT, jsh, 2 * p + 1, wave, lane, jB, gB);
        v_compute(packed, f0 + 2 * p, wave, lane, eA, jA, gA);
        // issue next A loads for f(2p+2), then consume B (A in flight)
        if (p < FPB_ / 2 - 1) {
            v_load_e(enc, f0 + 2 * p + 2, lane, eA);
            v_gather(decT, jsh, 2 * p + 2, wave, lane, jA, gA);
        }
        v_compute(packed, f0 + 2 * p + 1, wave, lane, eB, jB, gB);
    }
}

// ---------------------------------------------------------------------------
// out[bs,f] = sum_c up[bs, j]*v over the 16 connections of f. (unchanged)
// ---------------------------------------------------------------------------
__global__ __launch_bounds__(512) void k_out(const float* __restrict__ up,
                                             const unsigned int* __restrict__ packed,
                                             float* __restrict__ out) {
    __shared__ unsigned int rowp[F_];   // 64 KB
    int bs0  = (blockIdx.x >> 1) << 1;
    int half = blockIdx.x & 1;
    const float4* u0 = (const float4*)(up + (size_t)bs0 * F_);
    const float4* u1 = (const float4*)(up + (size_t)(bs0 + 1) * F_);
#pragma unroll
    for (int k = 0; k < 8; ++k) {
        int idx = threadIdx.x + k * 512;       // float4 index
        float4 a = u0[idx];
        float4 b = u1[idx];
        uint4 p;
        p.x = ((unsigned int)f2bf(b.x) << 16) | (unsigned int)f2bf(a.x);
        p.y = ((unsigned int)f2bf(b.y) << 16) | (unsigned int)f2bf(a.y);
        p.z = ((unsigned int)f2bf(b.z) << 16) | (unsigned int)f2bf(a.z);
        p.w = ((unsigned int)f2bf(b.w) << 16) | (unsigned int)f2bf(a.w);
        ((uint4*)rowp)[idx] = p;
    }
    __syncthreads();
    int f0 = half << 13;                       // 0 or 8192
#pragma unroll 4
    for (int it = 0; it < 16; ++it) {
        int f = f0 + threadIdx.x + it * 512;
        const uint4* sp = (const uint4*)(packed + ((size_t)f << 4));
        float a0 = 0.f, a1 = 0.f;
#pragma unroll
        for (int q = 0; q < 4; ++q) {
            uint4 w = sp[q];
#define CONN(ww) { unsigned int p_ = rowp[(ww) & 0xffffu];                  \
                   float v_ = __uint_as_float((ww) & 0xffff0000u);          \
                   a0 += __uint_as_float(p_ << 16) * v_;                    \
                   a1 += __uint_as_float(p_ & 0xffff0000u) * v_; }
            CONN(w.x) CONN(w.y) CONN(w.z) CONN(w.w)
#undef CONN
        }
        out[(size_t)bs0 * F_ + f] = a0;
        out[(size_t)(bs0 + 1) * F_ + f] = a1;
    }
}

extern "C" void kernel_launch(void* const* d_in, const int* in_sizes, int n_in,
                              void* d_out, int out_size, void* d_ws, size_t ws_size,
                              hipStream_t stream) {
    const float* up   = (const float*)d_in[0];  // up_facts   [B,S,F]
    const float* enc  = (const float*)d_in[1];  // down_encoder [F,D]
    const float* dec  = (const float*)d_in[2];  // up_decoder [D,F]
    // d_in[3] = i_indices, unused: i[m] = m >> 4 by construction
    const int*   jidx = (const int*)d_in[4];    // j_indices  [M]
    float*       out  = (float*)d_out;

    size_t decT_bytes = (size_t)F_ * D_ * sizeof(unsigned short);  // ~25.2 MB
    unsigned short* decT   = (unsigned short*)d_ws;
    unsigned int*   packed = (unsigned int*)((char*)d_ws + decT_bytes);  // 1 MB

    k_transpose_bf16<<<dim3(F_ / 64, D_ / 64), 256, 0, stream>>>(dec, decT);
    k_values<<<F_ / FPB_, 256, 0, stream>>>(enc, decT, jidx, packed);
    k_out<<<BS_, 512, 0, stream>>>(up, packed, out);
}

// Round 5
// 205.761 us; speedup vs baseline: 1.1021x; 1.1021x over previous
//
#include <hip/hip_runtime.h>
#include <hip/hip_bf16.h>

#define F_ 16384
#define D_ 768
#define C_ 16
#define BS_ 512
#define M_ (F_*C_)

static __device__ __forceinline__ float bf2f(unsigned short u) {
    return __uint_as_float(((unsigned int)u) << 16);
}
static __device__ __forceinline__ unsigned short f2bf(float f) {
    return __bfloat16_as_ushort(__float2bfloat16(f));
}

// int8 dot4: d = a.b + c over 4 packed signed bytes
#if __has_builtin(__builtin_amdgcn_sdot4)
static __device__ __forceinline__ int sdot4(unsigned int a, unsigned int b, int c) {
    return __builtin_amdgcn_sdot4((int)a, (int)b, c, false);
}
#else
static __device__ __forceinline__ int sdot4(unsigned int a, unsigned int b, int c) {
#pragma unroll
    for (int i = 0; i < 4; ++i)
        c += (int)(signed char)(a >> (8 * i)) * (int)(signed char)(b >> (8 * i));
    return c;
}
#endif

// ---------------------------------------------------------------------------
// Transpose + block-int8 quantize: up_decoder fp32 [D, F] -> dec8 int8 [F, D]
// with per-(f, 64d-block) fp32 scales [F][16] (12 used, padded to one 64 B
// line per row). The 64x64 tile's d-extent is exactly one scale block.
// q = round(v * 127/cmax); decode v ~= q * (cmax/127).
// ---------------------------------------------------------------------------
__global__ __launch_bounds__(256) void k_transpose_i8(const float* __restrict__ in,
                                                      unsigned char* __restrict__ out,
                                                      float* __restrict__ scales) {
    __shared__ float tile[64][65];      // [d_local][f_local], +1 pad
    __shared__ float pmax[4][64];       // partial |max| per quarter x f_local
    int c4 = threadIdx.x & 15;          // float4 column (f)
    int r  = threadIdx.x >> 4;          // 0..15 (d)
    int fbase = blockIdx.x * 64;
    int dbase = blockIdx.y * 64;
#pragma unroll
    for (int k = 0; k < 4; ++k) {
        int drow = r + k * 16;
        float4 v = *(const float4*)(in + (size_t)(dbase + drow) * F_ + fbase + c4 * 4);
        tile[drow][c4 * 4 + 0] = v.x;
        tile[drow][c4 * 4 + 1] = v.y;
        tile[drow][c4 * 4 + 2] = v.z;
        tile[drow][c4 * 4 + 3] = v.w;
    }
    __syncthreads();
    {
        int c = threadIdx.x & 63;       // f_local
        int q = threadIdx.x >> 6;       // quarter of d range
        float m = 0.f;
#pragma unroll
        for (int i = 0; i < 16; ++i)
            m = fmaxf(m, fabsf(tile[q * 16 + i][c]));
        pmax[q][c] = m;
    }
    __syncthreads();
    int dp = threadIdx.x & 15;          // uint index (4 d-values each)
    int fr = threadIdx.x >> 4;          // 0..15 (f)
#pragma unroll
    for (int k = 0; k < 4; ++k) {
        int frow = fr + k * 16;
        float cmax = fmaxf(fmaxf(pmax[0][frow], pmax[1][frow]),
                           fmaxf(pmax[2][frow], pmax[3][frow]));
        float s  = cmax * (1.f / 127.f);
        float rs = cmax > 0.f ? 127.f / cmax : 0.f;
        int q0 = __float2int_rn(tile[4 * dp + 0][frow] * rs);
        int q1 = __float2int_rn(tile[4 * dp + 1][frow] * rs);
        int q2 = __float2int_rn(tile[4 * dp + 2][frow] * rs);
        int q3 = __float2int_rn(tile[4 * dp + 3][frow] * rs);
        unsigned int p = (q0 & 0xff) | ((q1 & 0xff) << 8)
                       | ((q2 & 0xff) << 16) | ((q3 & 0xff) << 24);
        *(unsigned int*)(out + (size_t)(fbase + frow) * D_ + dbase + dp * 4) = p;
        if (dp == 0)
            scales[((size_t)(fbase + frow) << 4) + (dbase >> 6)] = s;
    }
}

// ---------------------------------------------------------------------------
// Per-connection value: dot(enc[f,:], dec8[j,:]) over D=768 via block-int8 x
// block-int8 sdot4 (exact int32 inner accumulation, scales applied per
// 64-block). One-shot R0 structure: one block per f, 4 waves x 4 conns, all
// gathers in flight before compute. Gathered row: 768 B data + one hot 64 B
// scale line. enc row is quantized in-register once per block (16-lane group
// max), amortized over the 16 connections.
// packed[m] = (bf16(value) << 16) | (u16)j.
// ---------------------------------------------------------------------------
__global__ __launch_bounds__(256) void k_values(const float* __restrict__ enc,
                                                const unsigned char* __restrict__ dec8,
                                                const float* __restrict__ scales,
                                                const int* __restrict__ jidx,
                                                unsigned int* __restrict__ packed) {
    int f = blockIdx.x;
    int lane = threadIdx.x & 63;
    int wave = threadIdx.x >> 6;        // 0..3
    const float4* erow = (const float4*)(enc + (size_t)f * D_);
    float4 e[3];
    e[0] = erow[lane];
    e[1] = erow[lane + 64];
    e[2] = erow[lane + 128];
    int4 j4 = *(const int4*)(jidx + (f << 4) + (wave << 2));
    int js[4] = {j4.x, j4.y, j4.z, j4.w};
    unsigned int g[4][3];
    float sd[4][3];
    int sb = lane >> 4;                 // scale sub-index within chunk
#pragma unroll
    for (int t = 0; t < 4; ++t) {
        const unsigned int* drow = (const unsigned int*)(dec8 + (size_t)js[t] * D_);
        g[t][0] = drow[lane];
        g[t][1] = drow[lane + 64];
        g[t][2] = drow[lane + 128];
        const float* srow = scales + ((size_t)js[t] << 4);
        sd[t][0] = srow[sb];
        sd[t][1] = srow[sb + 4];
        sd[t][2] = srow[sb + 8];
    }
    // quantize enc chunks to int8 with per-64d-block scale (16-lane groups:
    // lanes sharing lane>>4 hold the same 64-d block; xor offsets 1,2,4,8
    // stay within the group)
    unsigned int eq[3];
    float se[3];
#pragma unroll
    for (int k = 0; k < 3; ++k) {
        float4 v = e[k];
        float m = fmaxf(fmaxf(fabsf(v.x), fabsf(v.y)),
                        fmaxf(fabsf(v.z), fabsf(v.w)));
#pragma unroll
        for (int off = 1; off < 16; off <<= 1)
            m = fmaxf(m, __shfl_xor(m, off, 64));
        float rs = m > 0.f ? 127.f / m : 0.f;
        se[k] = m * (1.f / 127.f);
        int q0 = __float2int_rn(v.x * rs);
        int q1 = __float2int_rn(v.y * rs);
        int q2 = __float2int_rn(v.z * rs);
        int q3 = __float2int_rn(v.w * rs);
        eq[k] = (q0 & 0xff) | ((q1 & 0xff) << 8)
              | ((q2 & 0xff) << 16) | ((q3 & 0xff) << 24);
    }
#pragma unroll
    for (int t = 0; t < 4; ++t) {
        float acc = 0.f;
#pragma unroll
        for (int k = 0; k < 3; ++k) {
            int d = sdot4(eq[k], g[t][k], 0);
            acc = fmaf((float)d, se[k] * sd[t][k], acc);
        }
#pragma unroll
        for (int off = 32; off > 0; off >>= 1)
            acc += __shfl_down(acc, off, 64);
        if (lane == 0)
            packed[(f << 4) + (wave << 2) + t] =
                ((unsigned int)f2bf(acc) << 16) | (unsigned int)js[t];
    }
}

// ---------------------------------------------------------------------------
// out[bs,f] = sum_c up[bs, j]*v over the 16 connections of f. (unchanged)
// ---------------------------------------------------------------------------
__global__ __launch_bounds__(512) void k_out(const float* __restrict__ up,
                                             const unsigned int* __restrict__ packed,
                                             float* __restrict__ out) {
    __shared__ unsigned int rowp[F_];   // 64 KB
    int bs0  = (blockIdx.x >> 1) << 1;
    int half = blockIdx.x & 1;
    const float4* u0 = (const float4*)(up + (size_t)bs0 * F_);
    const float4* u1 = (const float4*)(up + (size_t)(bs0 + 1) * F_);
#pragma unroll
    for (int k = 0; k < 8; ++k) {
        int idx = threadIdx.x + k * 512;       // float4 index
        float4 a = u0[idx];
        float4 b = u1[idx];
        uint4 p;
        p.x = ((unsigned int)f2bf(b.x) << 16) | (unsigned int)f2bf(a.x);
        p.y = ((unsigned int)f2bf(b.y) << 16) | (unsigned int)f2bf(a.y);
        p.z = ((unsigned int)f2bf(b.z) << 16) | (unsigned int)f2bf(a.z);
        p.w = ((unsigned int)f2bf(b.w) << 16) | (unsigned int)f2bf(a.w);
        ((uint4*)rowp)[idx] = p;
    }
    __syncthreads();
    int f0 = half << 13;                       // 0 or 8192
#pragma unroll 4
    for (int it = 0; it < 16; ++it) {
        int f = f0 + threadIdx.x + it * 512;
        const uint4* sp = (const uint4*)(packed + ((size_t)f << 4));
        float a0 = 0.f, a1 = 0.f;
#pragma unroll
        for (int q = 0; q < 4; ++q) {
            uint4 w = sp[q];
#define CONN(ww) { unsigned int p_ = rowp[(ww) & 0xffffu];                  \
                   float v_ = __uint_as_float((ww) & 0xffff0000u);          \
                   a0 += __uint_as_float(p_ << 16) * v_;                    \
                   a1 += __uint_as_float(p_ & 0xffff0000u) * v_; }
            CONN(w.x) CONN(w.y) CONN(w.z) CONN(w.w)
#undef CONN
        }
        out[(size_t)bs0 * F_ + f] = a0;
        out[(size_t)(bs0 + 1) * F_ + f] = a1;
    }
}

extern "C" void kernel_launch(void* const* d_in, const int* in_sizes, int n_in,
                              void* d_out, int out_size, void* d_ws, size_t ws_size,
                              hipStream_t stream) {
    const float* up   = (const float*)d_in[0];  // up_facts   [B,S,F]
    const float* enc  = (const float*)d_in[1];  // down_encoder [F,D]
    const float* dec  = (const float*)d_in[2];  // up_decoder [D,F]
    // d_in[3] = i_indices, unused: i[m] = m >> 4 by construction
    const int*   jidx = (const int*)d_in[4];    // j_indices  [M]
    float*       out  = (float*)d_out;

    size_t dec8_bytes  = (size_t)F_ * D_;                 // 12.6 MB (int8)
    size_t scale_bytes = (size_t)F_ * 16 * sizeof(float); // 1 MB
    unsigned char* dec8   = (unsigned char*)d_ws;
    float*         scales = (float*)((char*)d_ws + dec8_bytes);
    unsigned int*  packed = (unsigned int*)((char*)d_ws + dec8_bytes + scale_bytes);

    k_transpose_i8<<<dim3(F_ / 64, D_ / 64), 256, 0, stream>>>(dec, dec8, scales);
    k_values<<<F_, 256, 0, stream>>>(enc, dec8, scales, jidx, packed);
    k_out<<<BS_, 512, 0, stream>>>(up, packed, out);
}